// Round 1
// baseline (7837.661 us; speedup 1.0000x reference)
//
#include <hip/hip_runtime.h>
#include <hip/hip_bf16.h>

#define NCLS 1000
#define BIMG 256
#define LSEQ 12
#define PFX  5
#define DMOD 512
#define NHEAD 8
#define NLAY 2
#define DFF  2048
#define DHEAD 64

__device__ __forceinline__ float gelu_tanh(float x) {
    const float c = 0.7978845608028654f;
    float t = tanhf(c * (x + 0.044715f * x * x * x));
    return 0.5f * x * (1.0f + t);
}

// ---------------- generic tiled SGEMM ----------------
// C(MxN,ldc) = A(MxK,lda) @ B ; B is KxN(ldb) row-major, or NxK(ldb) if BT.
// EPI: 0 = +bias; 1 = +bias,gelu; 2 = +bias,+R(residual); 3 = *exp(ls)*scaleM*scaleN
// K must be a multiple of 16.
template <int EPI, bool BT>
__global__ __launch_bounds__(256) void gemm64(
    const float* __restrict__ A, int lda,
    const float* __restrict__ B, int ldb,
    const float* __restrict__ bias,
    const float* __restrict__ R, int ldr,
    float* __restrict__ C, int ldc,
    int M, int N, int K,
    const float* __restrict__ scaleM,
    const float* __restrict__ scaleN,
    const float* __restrict__ lsp)
{
    __shared__ float As[16][65];
    __shared__ float Bs[16][65];
    const int t  = threadIdx.x;
    const int tx = t & 15, ty = t >> 4;
    const int bm = blockIdx.y * 64, bn = blockIdx.x * 64;

    float acc[4][4] = {};

    for (int k0 = 0; k0 < K; k0 += 16) {
        #pragma unroll
        for (int i = 0; i < 4; i++) {
            int e = t + i * 256;
            int r = e >> 4, c = e & 15;          // r: tile row (0..63), c: k (0..15)
            int gm = bm + r, gk = k0 + c;
            As[c][r] = (gm < M) ? A[(size_t)gm * lda + gk] : 0.f;
        }
        #pragma unroll
        for (int i = 0; i < 4; i++) {
            int e = t + i * 256;
            int r = e >> 6, c = e & 63;          // r: k (0..15), c: tile col (0..63)
            int gk = k0 + r, gn = bn + c;
            float v;
            if (BT) v = (gn < N) ? B[(size_t)gn * ldb + gk] : 0.f;
            else    v = (gn < N) ? B[(size_t)gk * ldb + gn] : 0.f;
            Bs[r][c] = v;
        }
        __syncthreads();
        #pragma unroll
        for (int kk = 0; kk < 16; kk++) {
            float a0[4], b0[4];
            #pragma unroll
            for (int i = 0; i < 4; i++) a0[i] = As[kk][ty * 4 + i];
            #pragma unroll
            for (int j = 0; j < 4; j++) b0[j] = Bs[kk][tx * 4 + j];
            #pragma unroll
            for (int i = 0; i < 4; i++)
                #pragma unroll
                for (int j = 0; j < 4; j++)
                    acc[i][j] += a0[i] * b0[j];
        }
        __syncthreads();
    }

    #pragma unroll
    for (int i = 0; i < 4; i++) {
        int gm = bm + ty * 4 + i;
        if (gm >= M) continue;
        #pragma unroll
        for (int j = 0; j < 4; j++) {
            int gn = bn + tx * 4 + j;
            if (gn >= N) continue;
            float v = acc[i][j];
            if (EPI == 0 || EPI == 1 || EPI == 2) { if (bias) v += bias[gn]; }
            if (EPI == 1) v = gelu_tanh(v);
            if (EPI == 2) v += R[(size_t)gm * ldr + gn];
            if (EPI == 3) v = expf(lsp[0]) * scaleM[gm] * scaleN[gn] * v;
            C[(size_t)gm * ldc + gn] = v;
        }
    }
}

// ---------------- LayerNorm: one block per row, cols = 512 ----------------
__global__ __launch_bounds__(256) void ln_kernel(
    const float* __restrict__ x, const float* __restrict__ g,
    const float* __restrict__ b, float* __restrict__ o)
{
    const int r = blockIdx.x, t = threadIdx.x;
    const float* xr = x + (size_t)r * DMOD;
    float v0 = xr[t], v1 = xr[t + 256];
    __shared__ float rs[256], rq[256];
    rs[t] = v0 + v1;
    rq[t] = v0 * v0 + v1 * v1;
    __syncthreads();
    for (int off = 128; off > 0; off >>= 1) {
        if (t < off) { rs[t] += rs[t + off]; rq[t] += rq[t + off]; }
        __syncthreads();
    }
    float mean = rs[0] * (1.0f / DMOD);
    float var  = rq[0] * (1.0f / DMOD) - mean * mean;
    float inv  = rsqrtf(var + 1e-5f);
    float* orow = o + (size_t)r * DMOD;
    orow[t]       = (v0 - mean) * inv * g[t]       + b[t];
    orow[t + 256] = (v1 - mean) * inv * g[t + 256] + b[t + 256];
}

// ---------------- inverse L2 row norm, cols = 512 ----------------
__global__ __launch_bounds__(256) void rownorm_inv(
    const float* __restrict__ x, float* __restrict__ inv)
{
    const int r = blockIdx.x, t = threadIdx.x;
    const float* xr = x + (size_t)r * DMOD;
    float v0 = xr[t], v1 = xr[t + 256];
    __shared__ float rq[256];
    rq[t] = v0 * v0 + v1 * v1;
    __syncthreads();
    for (int off = 128; off > 0; off >>= 1) {
        if (t < off) rq[t] += rq[t + off];
        __syncthreads();
    }
    if (t == 0) inv[r] = rsqrtf(rq[0]);
}

// ---------------- init / adjusted-prompt copy ----------------
__global__ __launch_bounds__(256) void adjust_kernel(
    const float* __restrict__ raw, const float* __restrict__ attr,
    float* __restrict__ x, int total)
{
    int i = blockIdx.x * 256 + threadIdx.x;
    if (i >= total) return;
    int nl = i >> 9;            // / 512
    int l  = nl % LSEQ;
    int n  = nl / LSEQ;
    float v = raw[i];
    if (attr != nullptr && l < PFX) v *= attr[n * PFX + l];
    x[i] = v;
}

// ---------------- attention: scores + mask ----------------
__global__ __launch_bounds__(256) void scores_kernel(
    const float* __restrict__ qkv, float* __restrict__ probs)
{
    int idx = blockIdx.x * 256 + threadIdx.x;
    if (idx >= NCLS * NHEAD * LSEQ * LSEQ) return;
    int ki = idx % LSEQ; int t = idx / LSEQ;
    int qi = t % LSEQ;  t /= LSEQ;
    int hh = t % NHEAD; int n = t / NHEAD;
    const float* q = qkv + ((size_t)(n * LSEQ + qi)) * (3 * DMOD) + hh * DHEAD;
    const float* k = qkv + ((size_t)(n * LSEQ + ki)) * (3 * DMOD) + DMOD + hh * DHEAD;
    float acc = 0.f;
    #pragma unroll
    for (int d = 0; d < DHEAD; d++) acc += q[d] * k[d];
    probs[idx] = acc * 0.125f + (ki > qi ? -1e9f : 0.f);
}

// ---------------- softmax over last dim (12) ----------------
__global__ __launch_bounds__(256) void softmax12(float* __restrict__ probs)
{
    int idx = blockIdx.x * 256 + threadIdx.x;
    if (idx >= NCLS * NHEAD * LSEQ) return;
    float* row = probs + (size_t)idx * LSEQ;
    float m = -1e30f;
    #pragma unroll
    for (int i = 0; i < LSEQ; i++) m = fmaxf(m, row[i]);
    float e[LSEQ]; float s = 0.f;
    #pragma unroll
    for (int i = 0; i < LSEQ; i++) { e[i] = expf(row[i] - m); s += e[i]; }
    float rcp = 1.0f / s;
    #pragma unroll
    for (int i = 0; i < LSEQ; i++) row[i] = e[i] * rcp;
}

// ---------------- attn @ V  -> (n, l, D) layout ----------------
__global__ __launch_bounds__(256) void attnv_kernel(
    const float* __restrict__ qkv, const float* __restrict__ probs,
    float* __restrict__ out)
{
    int idx = blockIdx.x * 256 + threadIdx.x;
    if (idx >= NCLS * NHEAD * LSEQ * DHEAD) return;
    int d = idx % DHEAD; int t = idx / DHEAD;
    int qi = t % LSEQ;  t /= LSEQ;
    int hh = t % NHEAD; int n = t / NHEAD;
    const float* pr = probs + (((size_t)(n * NHEAD + hh)) * LSEQ + qi) * LSEQ;
    const float* v  = qkv + (size_t)(n * LSEQ) * (3 * DMOD) + 2 * DMOD + hh * DHEAD + d;
    float acc = 0.f;
    #pragma unroll
    for (int ki = 0; ki < LSEQ; ki++) acc += pr[ki] * v[(size_t)ki * (3 * DMOD)];
    out[((size_t)(n * LSEQ + qi)) * DMOD + hh * DHEAD + d] = acc;
}

// ---------------- attr from last-layer probs ----------------
__global__ __launch_bounds__(256) void attr_kernel(
    const float* __restrict__ probs, float* __restrict__ attr)
{
    int n = blockIdx.x * 256 + threadIdx.x;
    if (n >= NCLS) return;
    float a[PFX]; float s = 0.f;
    #pragma unroll
    for (int p = 0; p < PFX; p++) {
        float acc = 0.f;
        for (int hh = 0; hh < NHEAD; hh++)
            acc += probs[(((size_t)(n * NHEAD + hh)) * LSEQ + (LSEQ - 1)) * LSEQ + p];
        a[p] = acc * (1.0f / NHEAD);
        s += a[p];
    }
    #pragma unroll
    for (int p = 0; p < PFX; p++) attr[n * PFX + p] = a[p] / (s + 1e-8f);
}

// ---------------- attribution output: mean over classes, broadcast ----------------
__global__ __launch_bounds__(256) void attribution_kernel(
    const float* __restrict__ attr, float* __restrict__ out2)
{
    int p = blockIdx.x, t = threadIdx.x;
    float s = 0.f;
    for (int n = t; n < NCLS; n += 256) s += attr[n * PFX + p];
    __shared__ float rq[256];
    rq[t] = s; __syncthreads();
    for (int off = 128; off > 0; off >>= 1) {
        if (t < off) rq[t] += rq[t + off];
        __syncthreads();
    }
    float mean = rq[0] * (1.0f / NCLS);
    out2[t * PFX + p] = mean;   // t = image row 0..255
}

extern "C" void kernel_launch(void* const* d_in, const int* in_sizes, int n_in,
                              void* d_out, int out_size, void* d_ws, size_t ws_size,
                              hipStream_t stream)
{
    const float* images = (const float*)d_in[0];
    const float* raw    = (const float*)d_in[1];
    const float* Wqkv   = (const float*)d_in[2];
    const float* bqkv   = (const float*)d_in[3];
    const float* Wo     = (const float*)d_in[4];
    const float* bo     = (const float*)d_in[5];
    const float* W1     = (const float*)d_in[6];
    const float* b1     = (const float*)d_in[7];
    const float* W2     = (const float*)d_in[8];
    const float* b2     = (const float*)d_in[9];
    const float* g1     = (const float*)d_in[10];
    const float* c1     = (const float*)d_in[11];
    const float* g2     = (const float*)d_in[12];
    const float* c2v    = (const float*)d_in[13];
    const float* tproj  = (const float*)d_in[14];
    const float* lsp    = (const float*)d_in[15];
    float* out = (float*)d_out;

    const int ROWS = NCLS * LSEQ;  // 12000

    float* ws    = (float*)d_ws;
    float* x     = ws;                              // 12000*512
    float* h     = x + (size_t)ROWS * DMOD;         // 12000*512
    float* S     = h + (size_t)ROWS * DMOD;         // 12000*1536 (qkv / ffn scratch)
    float* probs = S + (size_t)ROWS * 3 * DMOD;     // 1000*8*12*12
    float* attr  = probs + (size_t)NCLS * NHEAD * LSEQ * LSEQ;  // 5120 (padded)
    float* tf    = attr + 5120;                     // 1000*512
    float* invi  = tf + (size_t)NCLS * DMOD;        // 512 (padded)
    float* invt  = invi + 512;                      // 1024 (padded)

    auto run_pass = [&](bool useAttr) {
        {
            int total = ROWS * DMOD;
            adjust_kernel<<<(total + 255) / 256, 256, 0, stream>>>(
                raw, useAttr ? attr : nullptr, x, total);
        }
        for (int l = 0; l < NLAY; l++) {
            // h = LN1(x)
            ln_kernel<<<ROWS, 256, 0, stream>>>(x, g1 + l * DMOD, c1 + l * DMOD, h);
            // S = h @ Wqkv + bqkv   (12000 x 1536)
            gemm64<0, false><<<dim3(24, 188), 256, 0, stream>>>(
                h, DMOD, Wqkv + (size_t)l * DMOD * 3 * DMOD, 3 * DMOD,
                bqkv + l * 3 * DMOD, nullptr, 0, S, 3 * DMOD,
                ROWS, 3 * DMOD, DMOD, nullptr, nullptr, nullptr);
            // attention (writes probs, then h = attn-out in (n,l,D))
            scores_kernel<<<(NCLS * NHEAD * LSEQ * LSEQ + 255) / 256, 256, 0, stream>>>(S, probs);
            softmax12<<<(NCLS * NHEAD * LSEQ + 255) / 256, 256, 0, stream>>>(probs);
            attnv_kernel<<<(NCLS * NHEAD * LSEQ * DHEAD + 255) / 256, 256, 0, stream>>>(S, probs, h);
            // x = x + h @ Wo + bo
            gemm64<2, false><<<dim3(8, 188), 256, 0, stream>>>(
                h, DMOD, Wo + (size_t)l * DMOD * DMOD, DMOD,
                bo + l * DMOD, x, DMOD, x, DMOD,
                ROWS, DMOD, DMOD, nullptr, nullptr, nullptr);
            // h = LN2(x)
            ln_kernel<<<ROWS, 256, 0, stream>>>(x, g2 + l * DMOD, c2v + l * DMOD, h);
            // FFN in 2 row-chunks (scratch reuse): S = gelu(h@W1+b1); x += S@W2+b2
            for (int cc = 0; cc < 2; cc++) {
                int off = cc * 6000;
                gemm64<1, false><<<dim3(32, 94), 256, 0, stream>>>(
                    h + (size_t)off * DMOD, DMOD, W1 + (size_t)l * DMOD * DFF, DFF,
                    b1 + l * DFF, nullptr, 0, S, DFF,
                    6000, DFF, DMOD, nullptr, nullptr, nullptr);
                gemm64<2, false><<<dim3(8, 94), 256, 0, stream>>>(
                    S, DFF, W2 + (size_t)l * DFF * DMOD, DMOD,
                    b2 + l * DMOD, x + (size_t)off * DMOD, DMOD, x + (size_t)off * DMOD, DMOD,
                    6000, DMOD, DFF, nullptr, nullptr, nullptr);
            }
        }
    };

    run_pass(false);
    attr_kernel<<<4, 256, 0, stream>>>(probs, attr);
    run_pass(true);

    // tf = x2[:, -1, :] @ text_projection   (1000 x 512)
    gemm64<0, false><<<dim3(8, 16), 256, 0, stream>>>(
        x + 11 * DMOD, LSEQ * DMOD, tproj, DMOD, nullptr, nullptr, 0, tf, DMOD,
        NCLS, DMOD, DMOD, nullptr, nullptr, nullptr);
    rownorm_inv<<<NCLS, 256, 0, stream>>>(tf, invt);
    rownorm_inv<<<BIMG, 256, 0, stream>>>(images, invi);
    // logits = exp(ls) * norm(images) @ norm(tf)^T   (256 x 1000)
    gemm64<3, true><<<dim3(16, 4), 256, 0, stream>>>(
        images, DMOD, tf, DMOD, nullptr, nullptr, 0, out, NCLS,
        BIMG, NCLS, DMOD, invi, invt, lsp);
    // attribution = broadcast(mean_n attr)   (256 x 5)
    attribution_kernel<<<PFX, 256, 0, stream>>>(attr, out + (size_t)BIMG * NCLS);
}

// Round 2
// 1358.083 us; speedup vs baseline: 5.7711x; 5.7711x over previous
//
#include <hip/hip_runtime.h>
#include <hip/hip_bf16.h>

#define NCLS 1000
#define BIMG 256
#define LSEQ 12
#define PFX  5
#define DMOD 512
#define NHEAD 8
#define NLAY 2
#define DFF  2048
#define DHEAD 64

typedef __attribute__((ext_vector_type(8))) short bf16x8;
typedef __attribute__((ext_vector_type(4))) float f32x4;

__device__ __forceinline__ float gelu_tanh(float x) {
    const float c = 0.7978845608028654f;
    float t = tanhf(c * (x + 0.044715f * x * x * x));
    return 0.5f * x * (1.0f + t);
}

__device__ __forceinline__ void gload_lds16(const void* g, void* l) {
    __builtin_amdgcn_global_load_lds(
        (const __attribute__((address_space(1))) void*)g,
        (__attribute__((address_space(3))) void*)l, 16, 0, 0);
}

// ---------------- bf16 MFMA GEMM, m97 structure ----------------
// C = A(MxK bf16, row-major) @ B (supplied as Bt = N x K bf16 row-major)
// 128x128 tile, BK=32, 4 waves (2x2), each wave 64x64 via 4x4 16x16x32 MFMA.
// EPI: 0 = +bias -> bf16 Cb ; 1 = +bias,gelu -> bf16 Cb ; 2 = +bias,+R -> f32 Cf
// Requires: N % 128 == 0, K % 32 == 0, A/Bt readable up to 128-row tile pad.
template <int EPI>
__global__ __launch_bounds__(256) void gemm_mfma(
    const __hip_bfloat16* __restrict__ A, int lda,
    const __hip_bfloat16* __restrict__ Bt, int ldb,
    const float* __restrict__ bias,
    const float* __restrict__ R, int ldr,
    float* __restrict__ Cf, int ldcf,
    __hip_bfloat16* __restrict__ Cb, int ldcb,
    int M, int K)
{
    __shared__ unsigned short As[128 * 32];
    __shared__ unsigned short Bs[128 * 32];
    const int t    = threadIdx.x;
    const int wid  = t >> 6, lane = t & 63;
    const int wm   = wid >> 1, wn = wid & 1;
    const int bm   = blockIdx.y * 128, bn = blockIdx.x * 128;
    const int lr   = lane & 15, lk = lane >> 4;

    const int srow   = t >> 2;        // 0..63 staging row per round
    const int schunk = (t & 3) * 8;   // element offset within BK=32

    f32x4 acc[4][4] = {};

    const __hip_bfloat16* Abase = A  + (size_t)bm * lda;
    const __hip_bfloat16* Bbase = Bt + (size_t)bn * ldb;

    for (int k0 = 0; k0 < K; k0 += 32) {
        gload_lds16(Abase + (size_t)srow        * lda + k0 + schunk, (char*)As + wid * 1024);
        gload_lds16(Abase + (size_t)(srow + 64) * lda + k0 + schunk, (char*)As + 4096 + wid * 1024);
        gload_lds16(Bbase + (size_t)srow        * ldb + k0 + schunk, (char*)Bs + wid * 1024);
        gload_lds16(Bbase + (size_t)(srow + 64) * ldb + k0 + schunk, (char*)Bs + 4096 + wid * 1024);
        asm volatile("s_waitcnt vmcnt(0)" ::: "memory");
        __syncthreads();

        bf16x8 a[4], b[4];
        #pragma unroll
        for (int i = 0; i < 4; i++)
            a[i] = *reinterpret_cast<const bf16x8*>(&As[(wm * 64 + i * 16 + lr) * 32 + lk * 8]);
        #pragma unroll
        for (int j = 0; j < 4; j++)
            b[j] = *reinterpret_cast<const bf16x8*>(&Bs[(wn * 64 + j * 16 + lr) * 32 + lk * 8]);
        #pragma unroll
        for (int i = 0; i < 4; i++)
            #pragma unroll
            for (int j = 0; j < 4; j++)
                acc[i][j] = __builtin_amdgcn_mfma_f32_16x16x32_bf16(a[i], b[j], acc[i][j], 0, 0, 0);
        __syncthreads();
    }

    // C/D layout (m89-verified): col = lane&15, row = (lane>>4)*4 + reg
    #pragma unroll
    for (int i = 0; i < 4; i++) {
        int gm0 = bm + wm * 64 + i * 16 + lk * 4;
        #pragma unroll
        for (int j = 0; j < 4; j++) {
            int gn = bn + wn * 64 + j * 16 + lr;
            float bv = bias ? bias[gn] : 0.f;
            #pragma unroll
            for (int q = 0; q < 4; q++) {
                int gm = gm0 + q;
                if (gm >= M) continue;
                float v = acc[i][j][q] + bv;
                if (EPI == 1) v = gelu_tanh(v);
                if (EPI == 2) {
                    Cf[(size_t)gm * ldcf + gn] = v + R[(size_t)gm * ldr + gn];
                } else {
                    Cb[(size_t)gm * ldcb + gn] = __float2bfloat16(v);
                }
            }
        }
    }
}

// ---------------- weight transpose + f32->bf16: W (rows x cols) -> Wt (cols x rows) ----------------
__global__ __launch_bounds__(256) void transposeW(
    const float* __restrict__ W, int rows, int cols, __hip_bfloat16* __restrict__ Wt)
{
    __shared__ float tile[32][33];
    int bc = blockIdx.x * 32;
    int br = blockIdx.y * 32;
    int tx = threadIdx.x & 31, ty = threadIdx.x >> 5;
    #pragma unroll
    for (int i = 0; i < 4; i++) {
        int r = ty + i * 8;
        tile[r][tx] = W[(size_t)(br + r) * cols + bc + tx];
    }
    __syncthreads();
    #pragma unroll
    for (int i = 0; i < 4; i++) {
        int r = ty + i * 8;
        Wt[(size_t)(bc + r) * rows + br + tx] = __float2bfloat16(tile[tx][r]);
    }
}

// ---------------- fp32 tiled SGEMM (kept for the two small final GEMMs) ----------------
template <int EPI, bool BT>
__global__ __launch_bounds__(256) void gemm64(
    const float* __restrict__ A, int lda,
    const float* __restrict__ B, int ldb,
    const float* __restrict__ bias,
    float* __restrict__ C, int ldc,
    int M, int N, int K,
    const float* __restrict__ scaleM,
    const float* __restrict__ scaleN,
    const float* __restrict__ lsp)
{
    __shared__ float Asm[16][65];
    __shared__ float Bsm[16][65];
    const int t  = threadIdx.x;
    const int tx = t & 15, ty = t >> 4;
    const int bm = blockIdx.y * 64, bn = blockIdx.x * 64;

    float acc[4][4] = {};

    for (int k0 = 0; k0 < K; k0 += 16) {
        #pragma unroll
        for (int i = 0; i < 4; i++) {
            int e = t + i * 256;
            int r = e >> 4, c = e & 15;
            int gm = bm + r, gk = k0 + c;
            Asm[c][r] = (gm < M) ? A[(size_t)gm * lda + gk] : 0.f;
        }
        #pragma unroll
        for (int i = 0; i < 4; i++) {
            int e = t + i * 256;
            int r = e >> 6, c = e & 63;
            int gk = k0 + r, gn = bn + c;
            float v;
            if (BT) v = (gn < N) ? B[(size_t)gn * ldb + gk] : 0.f;
            else    v = (gn < N) ? B[(size_t)gk * ldb + gn] : 0.f;
            Bsm[r][c] = v;
        }
        __syncthreads();
        #pragma unroll
        for (int kk = 0; kk < 16; kk++) {
            float a0[4], b0[4];
            #pragma unroll
            for (int i = 0; i < 4; i++) a0[i] = Asm[kk][ty * 4 + i];
            #pragma unroll
            for (int j = 0; j < 4; j++) b0[j] = Bsm[kk][tx * 4 + j];
            #pragma unroll
            for (int i = 0; i < 4; i++)
                #pragma unroll
                for (int j = 0; j < 4; j++)
                    acc[i][j] += a0[i] * b0[j];
        }
        __syncthreads();
    }

    #pragma unroll
    for (int i = 0; i < 4; i++) {
        int gm = bm + ty * 4 + i;
        if (gm >= M) continue;
        #pragma unroll
        for (int j = 0; j < 4; j++) {
            int gn = bn + tx * 4 + j;
            if (gn >= N) continue;
            float v = acc[i][j];
            if (EPI == 0) { if (bias) v += bias[gn]; }
            if (EPI == 3) v = expf(lsp[0]) * scaleM[gm] * scaleN[gn] * v;
            C[(size_t)gm * ldc + gn] = v;
        }
    }
}

// ---------------- LayerNorm: one block per row, cols = 512, bf16 out ----------------
__global__ __launch_bounds__(256) void ln_bf16(
    const float* __restrict__ x, const float* __restrict__ g,
    const float* __restrict__ b, __hip_bfloat16* __restrict__ o)
{
    const int r = blockIdx.x, t = threadIdx.x;
    const float* xr = x + (size_t)r * DMOD;
    float v0 = xr[t], v1 = xr[t + 256];
    __shared__ float rs[256], rq[256];
    rs[t] = v0 + v1;
    rq[t] = v0 * v0 + v1 * v1;
    __syncthreads();
    for (int off = 128; off > 0; off >>= 1) {
        if (t < off) { rs[t] += rs[t + off]; rq[t] += rq[t + off]; }
        __syncthreads();
    }
    float mean = rs[0] * (1.0f / DMOD);
    float var  = rq[0] * (1.0f / DMOD) - mean * mean;
    float inv  = rsqrtf(var + 1e-5f);
    __hip_bfloat16* orow = o + (size_t)r * DMOD;
    orow[t]       = __float2bfloat16((v0 - mean) * inv * g[t]       + b[t]);
    orow[t + 256] = __float2bfloat16((v1 - mean) * inv * g[t + 256] + b[t + 256]);
}

// ---------------- inverse L2 row norm, cols = 512 ----------------
__global__ __launch_bounds__(256) void rownorm_inv(
    const float* __restrict__ x, float* __restrict__ inv)
{
    const int r = blockIdx.x, t = threadIdx.x;
    const float* xr = x + (size_t)r * DMOD;
    float v0 = xr[t], v1 = xr[t + 256];
    __shared__ float rq[256];
    rq[t] = v0 * v0 + v1 * v1;
    __syncthreads();
    for (int off = 128; off > 0; off >>= 1) {
        if (t < off) rq[t] += rq[t + off];
        __syncthreads();
    }
    if (t == 0) inv[r] = rsqrtf(rq[0]);
}

// ---------------- init / adjusted-prompt copy (x stays fp32) ----------------
__global__ __launch_bounds__(256) void adjust_kernel(
    const float* __restrict__ raw, const float* __restrict__ attr,
    float* __restrict__ x, int total)
{
    int i = blockIdx.x * 256 + threadIdx.x;
    if (i >= total) return;
    int nl = i >> 9;
    int l  = nl % LSEQ;
    int n  = nl / LSEQ;
    float v = raw[i];
    if (attr != nullptr && l < PFX) v *= attr[n * PFX + l];
    x[i] = v;
}

// ---------------- attention: scores + mask (bf16 qkv) ----------------
__global__ __launch_bounds__(256) void scores_kernel(
    const __hip_bfloat16* __restrict__ qkv, float* __restrict__ probs)
{
    int idx = blockIdx.x * 256 + threadIdx.x;
    if (idx >= NCLS * NHEAD * LSEQ * LSEQ) return;
    int ki = idx % LSEQ; int t = idx / LSEQ;
    int qi = t % LSEQ;  t /= LSEQ;
    int hh = t % NHEAD; int n = t / NHEAD;
    const __hip_bfloat16* q = qkv + ((size_t)(n * LSEQ + qi)) * (3 * DMOD) + hh * DHEAD;
    const __hip_bfloat16* k = qkv + ((size_t)(n * LSEQ + ki)) * (3 * DMOD) + DMOD + hh * DHEAD;
    float acc = 0.f;
    #pragma unroll
    for (int d = 0; d < DHEAD; d++) acc += __bfloat162float(q[d]) * __bfloat162float(k[d]);
    probs[idx] = acc * 0.125f + (ki > qi ? -1e9f : 0.f);
}

// ---------------- softmax over last dim (12) ----------------
__global__ __launch_bounds__(256) void softmax12(float* __restrict__ probs)
{
    int idx = blockIdx.x * 256 + threadIdx.x;
    if (idx >= NCLS * NHEAD * LSEQ) return;
    float* row = probs + (size_t)idx * LSEQ;
    float m = -1e30f;
    #pragma unroll
    for (int i = 0; i < LSEQ; i++) m = fmaxf(m, row[i]);
    float e[LSEQ]; float s = 0.f;
    #pragma unroll
    for (int i = 0; i < LSEQ; i++) { e[i] = expf(row[i] - m); s += e[i]; }
    float rcp = 1.0f / s;
    #pragma unroll
    for (int i = 0; i < LSEQ; i++) row[i] = e[i] * rcp;
}

// ---------------- attn @ V -> (n, l, D) layout, bf16 out ----------------
__global__ __launch_bounds__(256) void attnv_kernel(
    const __hip_bfloat16* __restrict__ qkv, const float* __restrict__ probs,
    __hip_bfloat16* __restrict__ out)
{
    int idx = blockIdx.x * 256 + threadIdx.x;
    if (idx >= NCLS * NHEAD * LSEQ * DHEAD) return;
    int d = idx % DHEAD; int t = idx / DHEAD;
    int qi = t % LSEQ;  t /= LSEQ;
    int hh = t % NHEAD; int n = t / NHEAD;
    const float* pr = probs + (((size_t)(n * NHEAD + hh)) * LSEQ + qi) * LSEQ;
    const __hip_bfloat16* v = qkv + (size_t)(n * LSEQ) * (3 * DMOD) + 2 * DMOD + hh * DHEAD + d;
    float acc = 0.f;
    #pragma unroll
    for (int ki = 0; ki < LSEQ; ki++) acc += pr[ki] * __bfloat162float(v[(size_t)ki * (3 * DMOD)]);
    out[((size_t)(n * LSEQ + qi)) * DMOD + hh * DHEAD + d] = __float2bfloat16(acc);
}

// ---------------- attr from last-layer probs ----------------
__global__ __launch_bounds__(256) void attr_kernel(
    const float* __restrict__ probs, float* __restrict__ attr)
{
    int n = blockIdx.x * 256 + threadIdx.x;
    if (n >= NCLS) return;
    float a[PFX]; float s = 0.f;
    #pragma unroll
    for (int p = 0; p < PFX; p++) {
        float acc = 0.f;
        for (int hh = 0; hh < NHEAD; hh++)
            acc += probs[(((size_t)(n * NHEAD + hh)) * LSEQ + (LSEQ - 1)) * LSEQ + p];
        a[p] = acc * (1.0f / NHEAD);
        s += a[p];
    }
    #pragma unroll
    for (int p = 0; p < PFX; p++) attr[n * PFX + p] = a[p] / (s + 1e-8f);
}

// ---------------- attribution output: mean over classes, broadcast ----------------
__global__ __launch_bounds__(256) void attribution_kernel(
    const float* __restrict__ attr, float* __restrict__ out2)
{
    int p = blockIdx.x, t = threadIdx.x;
    float s = 0.f;
    for (int n = t; n < NCLS; n += 256) s += attr[n * PFX + p];
    __shared__ float rq[256];
    rq[t] = s; __syncthreads();
    for (int off = 128; off > 0; off >>= 1) {
        if (t < off) rq[t] += rq[t + off];
        __syncthreads();
    }
    float mean = rq[0] * (1.0f / NCLS);
    out2[t * PFX + p] = mean;
}

extern "C" void kernel_launch(void* const* d_in, const int* in_sizes, int n_in,
                              void* d_out, int out_size, void* d_ws, size_t ws_size,
                              hipStream_t stream)
{
    const float* images = (const float*)d_in[0];
    const float* raw    = (const float*)d_in[1];
    const float* Wqkv   = (const float*)d_in[2];
    const float* bqkv   = (const float*)d_in[3];
    const float* Wo     = (const float*)d_in[4];
    const float* bo     = (const float*)d_in[5];
    const float* W1     = (const float*)d_in[6];
    const float* b1     = (const float*)d_in[7];
    const float* W2     = (const float*)d_in[8];
    const float* b2     = (const float*)d_in[9];
    const float* g1     = (const float*)d_in[10];
    const float* c1     = (const float*)d_in[11];
    const float* g2     = (const float*)d_in[12];
    const float* c2v    = (const float*)d_in[13];
    const float* tproj  = (const float*)d_in[14];
    const float* lsp    = (const float*)d_in[15];
    float* out = (float*)d_out;

    const int ROWS  = NCLS * LSEQ;   // 12000
    const int ROWSP = 12032;         // padded to 128-multiple for MFMA tile staging

    // ---- workspace layout (fp32 region, then bf16 region) ----
    float* ws    = (float*)d_ws;
    float* x     = ws;                                   // 12000*512
    float* probs = x + (size_t)ROWS * DMOD;              // 1000*8*12*12
    float* attr  = probs + (size_t)NCLS * NHEAD * LSEQ * LSEQ;
    float* tf    = attr + 5120;                          // 1000*512
    float* invi  = tf + (size_t)NCLS * DMOD;             // 512
    float* invt  = invi + 512;                           // 1024
    __hip_bfloat16* h_bf = (__hip_bfloat16*)(invt + 1024);          // 12032*512
    __hip_bfloat16* u_bf = h_bf + (size_t)ROWSP * DMOD;             // 12032*2048 (qkv / ffn-hidden union)
    __hip_bfloat16* wT   = u_bf + (size_t)ROWSP * DFF;              // 2 * 3,145,728

    const size_t LS = (size_t)(3 * DMOD) * DMOD + (size_t)DMOD * DMOD
                    + (size_t)DMOD * DFF + (size_t)DFF * DMOD;      // per-layer bf16 weights

    // ---- weights: transpose + bf16 convert (once per launch) ----
    for (int l = 0; l < NLAY; l++) {
        __hip_bfloat16* wqkvT = wT + l * LS;
        __hip_bfloat16* woT   = wqkvT + (size_t)(3 * DMOD) * DMOD;
        __hip_bfloat16* w1T   = woT + (size_t)DMOD * DMOD;
        __hip_bfloat16* w2T   = w1T + (size_t)DMOD * DFF;
        transposeW<<<dim3(3 * DMOD / 32, DMOD / 32), 256, 0, stream>>>(
            Wqkv + (size_t)l * DMOD * 3 * DMOD, DMOD, 3 * DMOD, wqkvT);
        transposeW<<<dim3(DMOD / 32, DMOD / 32), 256, 0, stream>>>(
            Wo + (size_t)l * DMOD * DMOD, DMOD, DMOD, woT);
        transposeW<<<dim3(DFF / 32, DMOD / 32), 256, 0, stream>>>(
            W1 + (size_t)l * DMOD * DFF, DMOD, DFF, w1T);
        transposeW<<<dim3(DMOD / 32, DFF / 32), 256, 0, stream>>>(
            W2 + (size_t)l * DFF * DMOD, DFF, DMOD, w2T);
    }

    auto run_pass = [&](bool useAttr) {
        {
            int total = ROWS * DMOD;
            adjust_kernel<<<(total + 255) / 256, 256, 0, stream>>>(
                raw, useAttr ? attr : nullptr, x, total);
        }
        for (int l = 0; l < NLAY; l++) {
            __hip_bfloat16* wqkvT = wT + l * LS;
            __hip_bfloat16* woT   = wqkvT + (size_t)(3 * DMOD) * DMOD;
            __hip_bfloat16* w1T   = woT + (size_t)DMOD * DMOD;
            __hip_bfloat16* w2T   = w1T + (size_t)DMOD * DFF;

            // h = LN1(x) -> bf16
            ln_bf16<<<ROWS, 256, 0, stream>>>(x, g1 + l * DMOD, c1 + l * DMOD, h_bf);
            // qkv = h @ Wqkv + bqkv -> bf16 (u_bf, ld = 1536)
            gemm_mfma<0><<<dim3(12, 94), 256, 0, stream>>>(
                h_bf, DMOD, wqkvT, DMOD, bqkv + l * 3 * DMOD,
                nullptr, 0, nullptr, 0, u_bf, 3 * DMOD, ROWS, DMOD);
            // attention
            scores_kernel<<<(NCLS * NHEAD * LSEQ * LSEQ + 255) / 256, 256, 0, stream>>>(u_bf, probs);
            softmax12<<<(NCLS * NHEAD * LSEQ + 255) / 256, 256, 0, stream>>>(probs);
            attnv_kernel<<<(NCLS * NHEAD * LSEQ * DHEAD + 255) / 256, 256, 0, stream>>>(u_bf, probs, h_bf);
            // x = x + attn_out @ Wo + bo   (fp32 residual)
            gemm_mfma<2><<<dim3(4, 94), 256, 0, stream>>>(
                h_bf, DMOD, woT, DMOD, bo + l * DMOD,
                x, DMOD, x, DMOD, nullptr, 0, ROWS, DMOD);
            // h = LN2(x) -> bf16
            ln_bf16<<<ROWS, 256, 0, stream>>>(x, g2 + l * DMOD, c2v + l * DMOD, h_bf);
            // g = gelu(h @ W1 + b1) -> bf16 (u_bf, ld = 2048)
            gemm_mfma<1><<<dim3(16, 94), 256, 0, stream>>>(
                h_bf, DMOD, w1T, DMOD, b1 + l * DFF,
                nullptr, 0, nullptr, 0, u_bf, DFF, ROWS, DMOD);
            // x = x + g @ W2 + b2   (fp32 residual)
            gemm_mfma<2><<<dim3(4, 94), 256, 0, stream>>>(
                u_bf, DFF, w2T, DFF, b2 + l * DMOD,
                x, DMOD, x, DMOD, nullptr, 0, ROWS, DFF);
        }
    };

    run_pass(false);
    attr_kernel<<<4, 256, 0, stream>>>(probs, attr);
    run_pass(true);

    // tf = x2[:, -1, :] @ text_projection   (fp32 for accuracy)
    gemm64<0, false><<<dim3(8, 16), 256, 0, stream>>>(
        x + 11 * DMOD, LSEQ * DMOD, tproj, DMOD, nullptr, tf, DMOD,
        NCLS, DMOD, DMOD, nullptr, nullptr, nullptr);
    rownorm_inv<<<NCLS, 256, 0, stream>>>(tf, invt);
    rownorm_inv<<<BIMG, 256, 0, stream>>>(images, invi);
    // logits = exp(ls) * norm(images) @ norm(tf)^T
    gemm64<3, true><<<dim3(16, 4), 256, 0, stream>>>(
        images, DMOD, tf, DMOD, nullptr, out, NCLS,
        BIMG, NCLS, DMOD, invi, invt, lsp);
    // attribution = broadcast(mean_n attr)
    attribution_kernel<<<PFX, 256, 0, stream>>>(attr, out + (size_t)BIMG * NCLS);
}

// Round 3
// 1149.330 us; speedup vs baseline: 6.8193x; 1.1816x over previous
//
#include <hip/hip_runtime.h>
#include <hip/hip_bf16.h>

#define NCLS 1000
#define BIMG 256
#define LSEQ 12
#define PFX  5
#define DMOD 512
#define NHEAD 8
#define NLAY 2
#define DFF  2048
#define DHEAD 64

typedef __attribute__((ext_vector_type(8))) short bf16x8;
typedef __attribute__((ext_vector_type(4))) float f32x4;

__device__ __forceinline__ float gelu_tanh(float x) {
    const float c = 0.7978845608028654f;
    float t = tanhf(c * (x + 0.044715f * x * x * x));
    return 0.5f * x * (1.0f + t);
}

__device__ __forceinline__ float bf2f(unsigned short u) {
    unsigned int x = ((unsigned int)u) << 16;
    float f; __builtin_memcpy(&f, &x, 4); return f;
}

__device__ __forceinline__ void gload_lds16(const void* g, void* l) {
    __builtin_amdgcn_global_load_lds(
        (const __attribute__((address_space(1))) void*)g,
        (__attribute__((address_space(3))) void*)l, 16, 0, 0);
}

// ---------------- bf16 MFMA GEMM, m97 structure + 2-phase double-buffer ----------------
// C = A(MxK bf16, row-major) @ B (supplied as Bt = N x K bf16 row-major)
// 128x128 tile, BK=32, 4 waves (2x2), each wave 64x64 via 4x4 16x16x32 MFMA.
// EPI: 0=+bias->bf16 ; 1=+bias,gelu->bf16 ; 2=+bias,+R->f32 ; 3=exp(ls)*sM*sN->f32 (gn<Nreal guard)
template <int EPI>
__global__ __launch_bounds__(256) void gemm_mfma(
    const __hip_bfloat16* __restrict__ A, int lda,
    const __hip_bfloat16* __restrict__ Bt, int ldb,
    const float* __restrict__ bias,
    const float* __restrict__ R, int ldr,
    float* __restrict__ Cf, int ldcf,
    __hip_bfloat16* __restrict__ Cb, int ldcb,
    int M, int K, int Nreal,
    const float* __restrict__ scaleM,
    const float* __restrict__ scaleN,
    const float* __restrict__ lsp)
{
    __shared__ unsigned short As[2][128 * 32];
    __shared__ unsigned short Bs[2][128 * 32];
    const int t    = threadIdx.x;
    const int wid  = t >> 6, lane = t & 63;
    const int wm   = wid >> 1, wn = wid & 1;
    const int bm   = blockIdx.y * 128, bn = blockIdx.x * 128;
    const int lr   = lane & 15, lk = lane >> 4;

    const int srow   = t >> 2;        // 0..63 staging row per round
    const int schunk = (t & 3) * 8;   // element offset within BK=32

    f32x4 acc[4][4] = {};

    const __hip_bfloat16* Abase = A  + (size_t)bm * lda;
    const __hip_bfloat16* Bbase = Bt + (size_t)bn * ldb;

    auto STAGE = [&](int k0, int buf) {
        char* ab = (char*)&As[buf][0];
        char* bb = (char*)&Bs[buf][0];
        gload_lds16(Abase + (size_t)srow        * lda + k0 + schunk, ab + wid * 1024);
        gload_lds16(Abase + (size_t)(srow + 64) * lda + k0 + schunk, ab + 4096 + wid * 1024);
        gload_lds16(Bbase + (size_t)srow        * ldb + k0 + schunk, bb + wid * 1024);
        gload_lds16(Bbase + (size_t)(srow + 64) * ldb + k0 + schunk, bb + 4096 + wid * 1024);
    };

    STAGE(0, 0);
    asm volatile("s_waitcnt vmcnt(0)" ::: "memory");
    __syncthreads();

    int cur = 0;
    for (int k0 = 0; k0 < K; k0 += 32) {
        if (k0 + 32 < K) STAGE(k0 + 32, cur ^ 1);   // prefetch next tile (in flight over MFMA)

        bf16x8 a[4], b[4];
        #pragma unroll
        for (int i = 0; i < 4; i++)
            a[i] = *reinterpret_cast<const bf16x8*>(&As[cur][(wm * 64 + i * 16 + lr) * 32 + lk * 8]);
        #pragma unroll
        for (int j = 0; j < 4; j++)
            b[j] = *reinterpret_cast<const bf16x8*>(&Bs[cur][(wn * 64 + j * 16 + lr) * 32 + lk * 8]);
        #pragma unroll
        for (int i = 0; i < 4; i++)
            #pragma unroll
            for (int j = 0; j < 4; j++)
                acc[i][j] = __builtin_amdgcn_mfma_f32_16x16x32_bf16(a[i], b[j], acc[i][j], 0, 0, 0);

        asm volatile("s_waitcnt vmcnt(0)" ::: "memory");
        __syncthreads();
        cur ^= 1;
    }

    // C/D layout (m89-verified): col = lane&15, row = (lane>>4)*4 + reg
    #pragma unroll
    for (int i = 0; i < 4; i++) {
        int gm0 = bm + wm * 64 + i * 16 + lk * 4;
        #pragma unroll
        for (int j = 0; j < 4; j++) {
            int gn = bn + wn * 64 + j * 16 + lr;
            float bv = (EPI <= 2 && bias) ? bias[gn] : 0.f;
            #pragma unroll
            for (int q = 0; q < 4; q++) {
                int gm = gm0 + q;
                if (gm >= M) continue;
                float v = acc[i][j][q] + bv;
                if (EPI == 1) v = gelu_tanh(v);
                if (EPI == 2) {
                    Cf[(size_t)gm * ldcf + gn] = v + R[(size_t)gm * ldr + gn];
                } else if (EPI == 3) {
                    if (gn < Nreal)
                        Cf[(size_t)gm * ldcf + gn] = expf(lsp[0]) * scaleM[gm] * scaleN[gn] * acc[i][j][q];
                } else {
                    Cb[(size_t)gm * ldcb + gn] = __float2bfloat16(v);
                }
            }
        }
    }
}

// ---------------- weight transpose + f32->bf16: W (rows x cols) -> Wt (cols x rows) ----------------
__global__ __launch_bounds__(256) void transposeW(
    const float* __restrict__ W, int rows, int cols, __hip_bfloat16* __restrict__ Wt)
{
    __shared__ float tile[32][33];
    int bc = blockIdx.x * 32;
    int br = blockIdx.y * 32;
    int tx = threadIdx.x & 31, ty = threadIdx.x >> 5;
    #pragma unroll
    for (int i = 0; i < 4; i++) {
        int r = ty + i * 8;
        tile[r][tx] = W[(size_t)(br + r) * cols + bc + tx];
    }
    __syncthreads();
    #pragma unroll
    for (int i = 0; i < 4; i++) {
        int r = ty + i * 8;
        Wt[(size_t)(bc + r) * rows + br + tx] = __float2bfloat16(tile[tx][r]);
    }
}

// ---------------- LayerNorm: one block per row, cols = 512, bf16 out ----------------
__global__ __launch_bounds__(256) void ln_bf16(
    const float* __restrict__ x, const float* __restrict__ g,
    const float* __restrict__ b, __hip_bfloat16* __restrict__ o)
{
    const int r = blockIdx.x, t = threadIdx.x;
    const float* xr = x + (size_t)r * DMOD;
    float v0 = xr[t], v1 = xr[t + 256];
    __shared__ float rs[256], rq[256];
    rs[t] = v0 + v1;
    rq[t] = v0 * v0 + v1 * v1;
    __syncthreads();
    for (int off = 128; off > 0; off >>= 1) {
        if (t < off) { rs[t] += rs[t + off]; rq[t] += rq[t + off]; }
        __syncthreads();
    }
    float mean = rs[0] * (1.0f / DMOD);
    float var  = rq[0] * (1.0f / DMOD) - mean * mean;
    float inv  = rsqrtf(var + 1e-5f);
    __hip_bfloat16* orow = o + (size_t)r * DMOD;
    orow[t]       = __float2bfloat16((v0 - mean) * inv * g[t]       + b[t]);
    orow[t + 256] = __float2bfloat16((v1 - mean) * inv * g[t + 256] + b[t + 256]);
}

// ---------------- inverse L2 row norm, fp32 input ----------------
__global__ __launch_bounds__(256) void rownorm_inv(
    const float* __restrict__ x, float* __restrict__ inv)
{
    const int r = blockIdx.x, t = threadIdx.x;
    const float* xr = x + (size_t)r * DMOD;
    float v0 = xr[t], v1 = xr[t + 256];
    __shared__ float rq[256];
    rq[t] = v0 * v0 + v1 * v1;
    __syncthreads();
    for (int off = 128; off > 0; off >>= 1) {
        if (t < off) rq[t] += rq[t + off];
        __syncthreads();
    }
    if (t == 0) inv[r] = rsqrtf(rq[0]);
}

// ---------------- inverse L2 row norm, bf16 input ----------------
__global__ __launch_bounds__(256) void rownorm_inv_bf16(
    const __hip_bfloat16* __restrict__ x, float* __restrict__ inv)
{
    const int r = blockIdx.x, t = threadIdx.x;
    const unsigned short* xr = (const unsigned short*)(x + (size_t)r * DMOD);
    float v0 = bf2f(xr[t]), v1 = bf2f(xr[t + 256]);
    __shared__ float rq[256];
    rq[t] = v0 * v0 + v1 * v1;
    __syncthreads();
    for (int off = 128; off > 0; off >>= 1) {
        if (t < off) rq[t] += rq[t + off];
        __syncthreads();
    }
    if (t == 0) inv[r] = rsqrtf(rq[0]);
}

// ---------------- init / adjusted-prompt copy (x stays fp32) ----------------
__global__ __launch_bounds__(256) void adjust_kernel(
    const float* __restrict__ raw, const float* __restrict__ attr,
    float* __restrict__ x, int total)
{
    int i = blockIdx.x * 256 + threadIdx.x;
    if (i >= total) return;
    int nl = i >> 9;
    int l  = nl % LSEQ;
    int n  = nl / LSEQ;
    float v = raw[i];
    if (attr != nullptr && l < PFX) v *= attr[n * PFX + l];
    x[i] = v;
}

// ---------------- fused attention: block = one class n ----------------
// qkv rows staged in LDS; scores+softmax in-LDS; out = attn@V; last-row probs -> plast
__global__ __launch_bounds__(256) void attn_fused(
    const __hip_bfloat16* __restrict__ qkv,   // [n*12 + qi][1536]
    __hip_bfloat16* __restrict__ out,         // [n*12 + qi][512]
    float* __restrict__ plast)                // [n][8][12]
{
    const int n = blockIdx.x, t = threadIdx.x;
    __shared__ __hip_bfloat16 S[12][1544];    // cols: 0-511 Q, 512-1023 K, 1024-1535 V
    __shared__ float P[8][12][13];

    const __hip_bfloat16* src = qkv + (size_t)n * LSEQ * (3 * DMOD);
    for (int c = t; c < 12 * 192; c += 256) {     // 192 8-elem chunks per row
        int r = c / 192, col = (c % 192) * 8;
        *reinterpret_cast<bf16x8*>(&S[r][col]) =
            *reinterpret_cast<const bf16x8*>(&src[(size_t)r * (3 * DMOD) + col]);
    }
    __syncthreads();

    const int h = t >> 5, l32 = t & 31;
    if (l32 < LSEQ) {
        const int qi = l32;
        float sc[LSEQ];
        #pragma unroll
        for (int ki = 0; ki < LSEQ; ki++) {
            float acc = 0.f;
            #pragma unroll
            for (int d = 0; d < DHEAD; d += 8) {
                bf16x8 qv = *reinterpret_cast<const bf16x8*>(&S[qi][h * 64 + d]);
                bf16x8 kv = *reinterpret_cast<const bf16x8*>(&S[ki][512 + h * 64 + d]);
                #pragma unroll
                for (int e = 0; e < 8; e++)
                    acc += bf2f((unsigned short)qv[e]) * bf2f((unsigned short)kv[e]);
            }
            sc[ki] = acc * 0.125f + (ki > qi ? -1e9f : 0.f);
        }
        float m = sc[0];
        #pragma unroll
        for (int ki = 1; ki < LSEQ; ki++) m = fmaxf(m, sc[ki]);
        float e[LSEQ], s = 0.f;
        #pragma unroll
        for (int ki = 0; ki < LSEQ; ki++) { e[ki] = expf(sc[ki] - m); s += e[ki]; }
        float rcp = 1.0f / s;
        #pragma unroll
        for (int ki = 0; ki < LSEQ; ki++) P[h][qi][ki] = e[ki] * rcp;
        if (qi == LSEQ - 1) {
            #pragma unroll
            for (int ki = 0; ki < LSEQ; ki++)
                plast[((size_t)n * NHEAD + h) * LSEQ + ki] = e[ki] * rcp;
        }
    }
    __syncthreads();

    // PV: 32 lanes per head, each lane 2 d-dims
    #pragma unroll
    for (int dd = 0; dd < 2; dd++) {
        int d = l32 * 2 + dd;
        for (int qi = 0; qi < LSEQ; qi++) {
            float acc = 0.f;
            #pragma unroll
            for (int ki = 0; ki < LSEQ; ki++)
                acc += P[h][qi][ki] * bf2f(((const unsigned short*)&S[ki][1024 + h * 64])[d]);
            out[((size_t)(n * LSEQ + qi)) * DMOD + h * 64 + d] = __float2bfloat16(acc);
        }
    }
}

// ---------------- attr from plast ----------------
__global__ __launch_bounds__(256) void attr_kernel(
    const float* __restrict__ plast, float* __restrict__ attr)
{
    int n = blockIdx.x * 256 + threadIdx.x;
    if (n >= NCLS) return;
    float a[PFX]; float s = 0.f;
    #pragma unroll
    for (int p = 0; p < PFX; p++) {
        float acc = 0.f;
        for (int hh = 0; hh < NHEAD; hh++)
            acc += plast[((size_t)n * NHEAD + hh) * LSEQ + p];
        a[p] = acc * (1.0f / NHEAD);
        s += a[p];
    }
    #pragma unroll
    for (int p = 0; p < PFX; p++) attr[n * PFX + p] = a[p] / (s + 1e-8f);
}

// ---------------- final prep: extract x2[:,-1,:] -> bf16 (padded), images -> bf16, zero tf pad ----------------
__global__ __launch_bounds__(256) void finalize_prep(
    const float* __restrict__ x, const float* __restrict__ images,
    __hip_bfloat16* __restrict__ xlast,   // [1024][512]
    __hip_bfloat16* __restrict__ img_bf,  // [256][512]
    __hip_bfloat16* __restrict__ tf_bf)   // [1024][512] (zero pad rows 1000..1023)
{
    int idx = blockIdx.x * 256 + threadIdx.x;
    const int NX = 1024 * DMOD, NI = BIMG * DMOD, NP = 24 * DMOD;
    if (idx < NX) {
        int r = idx >> 9, d = idx & 511;
        xlast[idx] = (r < NCLS) ? __float2bfloat16(x[((size_t)r * LSEQ + (LSEQ - 1)) * DMOD + d])
                                : __float2bfloat16(0.f);
    } else if (idx < NX + NI) {
        int j = idx - NX;
        img_bf[j] = __float2bfloat16(images[j]);
    } else if (idx < NX + NI + NP) {
        int j = idx - NX - NI;
        tf_bf[(size_t)NCLS * DMOD + j] = __float2bfloat16(0.f);
    }
}

// ---------------- attribution output: mean over classes, broadcast ----------------
__global__ __launch_bounds__(256) void attribution_kernel(
    const float* __restrict__ attr, float* __restrict__ out2)
{
    int p = blockIdx.x, t = threadIdx.x;
    float s = 0.f;
    for (int n = t; n < NCLS; n += 256) s += attr[n * PFX + p];
    __shared__ float rq[256];
    rq[t] = s; __syncthreads();
    for (int off = 128; off > 0; off >>= 1) {
        if (t < off) rq[t] += rq[t + off];
        __syncthreads();
    }
    float mean = rq[0] * (1.0f / NCLS);
    out2[t * PFX + p] = mean;
}

extern "C" void kernel_launch(void* const* d_in, const int* in_sizes, int n_in,
                              void* d_out, int out_size, void* d_ws, size_t ws_size,
                              hipStream_t stream)
{
    const float* images = (const float*)d_in[0];
    const float* raw    = (const float*)d_in[1];
    const float* Wqkv   = (const float*)d_in[2];
    const float* bqkv   = (const float*)d_in[3];
    const float* Wo     = (const float*)d_in[4];
    const float* bo     = (const float*)d_in[5];
    const float* W1     = (const float*)d_in[6];
    const float* b1     = (const float*)d_in[7];
    const float* W2     = (const float*)d_in[8];
    const float* b2     = (const float*)d_in[9];
    const float* g1     = (const float*)d_in[10];
    const float* c1     = (const float*)d_in[11];
    const float* g2     = (const float*)d_in[12];
    const float* c2v    = (const float*)d_in[13];
    const float* tproj  = (const float*)d_in[14];
    const float* lsp    = (const float*)d_in[15];
    float* out = (float*)d_out;

    const int ROWS  = NCLS * LSEQ;   // 12000
    const int ROWSP = 12032;         // padded to 128-multiple for MFMA tile staging

    // ---- workspace layout: fp32 region, then bf16 region (16B-aligned boundaries) ----
    float* ws    = (float*)d_ws;
    float* x     = ws;                                     // 12000*512
    float* plast = x + (size_t)ROWS * DMOD;                // 1000*8*12
    float* attr  = plast + (size_t)NCLS * NHEAD * LSEQ;    // 5120 (padded)
    float* invi  = attr + 5120;                            // 512
    float* invt  = invi + 512;                             // 1024
    __hip_bfloat16* h_bf   = (__hip_bfloat16*)(invt + 1024);        // 12032*512
    __hip_bfloat16* u_bf   = h_bf + (size_t)ROWSP * DMOD;           // 12032*2048 (qkv / ffn union)
    __hip_bfloat16* wT     = u_bf + (size_t)ROWSP * DFF;            // 2 * 3,145,728
    const size_t LS = (size_t)(3 * DMOD) * DMOD + (size_t)DMOD * DMOD
                    + (size_t)DMOD * DFF + (size_t)DFF * DMOD;
    __hip_bfloat16* tprojT = wT + NLAY * LS;                        // 512*512
    __hip_bfloat16* xlast  = tprojT + (size_t)DMOD * DMOD;          // 1024*512
    __hip_bfloat16* img_bf = xlast + (size_t)1024 * DMOD;           // 256*512
    __hip_bfloat16* tf_bf  = img_bf + (size_t)BIMG * DMOD;          // 1024*512

    // ---- weights: transpose + bf16 convert (per launch) ----
    for (int l = 0; l < NLAY; l++) {
        __hip_bfloat16* wqkvT = wT + l * LS;
        __hip_bfloat16* woT   = wqkvT + (size_t)(3 * DMOD) * DMOD;
        __hip_bfloat16* w1T   = woT + (size_t)DMOD * DMOD;
        __hip_bfloat16* w2T   = w1T + (size_t)DMOD * DFF;
        transposeW<<<dim3(3 * DMOD / 32, DMOD / 32), 256, 0, stream>>>(
            Wqkv + (size_t)l * DMOD * 3 * DMOD, DMOD, 3 * DMOD, wqkvT);
        transposeW<<<dim3(DMOD / 32, DMOD / 32), 256, 0, stream>>>(
            Wo + (size_t)l * DMOD * DMOD, DMOD, DMOD, woT);
        transposeW<<<dim3(DFF / 32, DMOD / 32), 256, 0, stream>>>(
            W1 + (size_t)l * DMOD * DFF, DMOD, DFF, w1T);
        transposeW<<<dim3(DMOD / 32, DFF / 32), 256, 0, stream>>>(
            W2 + (size_t)l * DFF * DMOD, DFF, DMOD, w2T);
    }
    transposeW<<<dim3(DMOD / 32, DMOD / 32), 256, 0, stream>>>(tproj, DMOD, DMOD, tprojT);

    auto run_pass = [&](bool useAttr) {
        {
            int total = ROWS * DMOD;
            adjust_kernel<<<(total + 255) / 256, 256, 0, stream>>>(
                raw, useAttr ? attr : nullptr, x, total);
        }
        for (int l = 0; l < NLAY; l++) {
            __hip_bfloat16* wqkvT = wT + l * LS;
            __hip_bfloat16* woT   = wqkvT + (size_t)(3 * DMOD) * DMOD;
            __hip_bfloat16* w1T   = woT + (size_t)DMOD * DMOD;
            __hip_bfloat16* w2T   = w1T + (size_t)DMOD * DFF;

            ln_bf16<<<ROWS, 256, 0, stream>>>(x, g1 + l * DMOD, c1 + l * DMOD, h_bf);
            gemm_mfma<0><<<dim3(12, 94), 256, 0, stream>>>(
                h_bf, DMOD, wqkvT, DMOD, bqkv + l * 3 * DMOD,
                nullptr, 0, nullptr, 0, u_bf, 3 * DMOD, ROWS, DMOD,
                3 * DMOD, nullptr, nullptr, nullptr);
            attn_fused<<<NCLS, 256, 0, stream>>>(u_bf, h_bf, plast);
            gemm_mfma<2><<<dim3(4, 94), 256, 0, stream>>>(
                h_bf, DMOD, woT, DMOD, bo + l * DMOD,
                x, DMOD, x, DMOD, nullptr, 0, ROWS, DMOD,
                DMOD, nullptr, nullptr, nullptr);
            ln_bf16<<<ROWS, 256, 0, stream>>>(x, g2 + l * DMOD, c2v + l * DMOD, h_bf);
            gemm_mfma<1><<<dim3(16, 94), 256, 0, stream>>>(
                h_bf, DMOD, w1T, DMOD, b1 + l * DFF,
                nullptr, 0, nullptr, 0, u_bf, DFF, ROWS, DMOD,
                DFF, nullptr, nullptr, nullptr);
            gemm_mfma<2><<<dim3(4, 94), 256, 0, stream>>>(
                u_bf, DFF, w2T, DFF, b2 + l * DMOD,
                x, DMOD, x, DMOD, nullptr, 0, ROWS, DFF,
                DMOD, nullptr, nullptr, nullptr);
        }
    };

    run_pass(false);
    attr_kernel<<<4, 256, 0, stream>>>(plast, attr);
    run_pass(true);

    // final head
    {
        int total = 1024 * DMOD + BIMG * DMOD + 24 * DMOD;
        finalize_prep<<<(total + 255) / 256, 256, 0, stream>>>(x, images, xlast, img_bf, tf_bf);
    }
    // tf = xlast @ tproj  (1000x512, bf16 out)
    gemm_mfma<0><<<dim3(4, 8), 256, 0, stream>>>(
        xlast, DMOD, tprojT, DMOD, nullptr,
        nullptr, 0, nullptr, 0, tf_bf, DMOD, NCLS, DMOD,
        DMOD, nullptr, nullptr, nullptr);
    rownorm_inv_bf16<<<NCLS, 256, 0, stream>>>(tf_bf, invt);
    rownorm_inv<<<BIMG, 256, 0, stream>>>(images, invi);
    // logits = exp(ls) * invi[m] * invt[n] * (img_bf @ tf_bf^T)   (256 x 1000)
    gemm_mfma<3><<<dim3(8, 2), 256, 0, stream>>>(
        img_bf, DMOD, tf_bf, DMOD, nullptr,
        nullptr, 0, out, NCLS, nullptr, 0, BIMG, DMOD,
        NCLS, invi, invt, lsp);
    attribution_kernel<<<PFX, 256, 0, stream>>>(attr, out + (size_t)BIMG * NCLS);
}